// Round 1
// baseline (120.690 us; speedup 1.0000x reference)
//
#include <hip/hip_runtime.h>

// Problem geometry (fixed by the reference)
#define HH    2160
#define WW    3840
#define CCH   3
#define CROPC 3
#define NN    (HH - 2*CROPC)   // 2154 output rows
#define WFLAT (WW * CCH)       // 11520 flat columns (col-major-in-channel)

constexpr int TY  = 32;        // output rows per tile
constexpr int TXF = 128;       // output flat-cols per tile (WFLAT % TXF == 0 -> 90 tiles)
constexpr int SX  = TXF + 18;  // v/v2 tile width: halo 12 left (c-4) + 6 right (c+2)
constexpr int XR  = TY + 6;    // x rows needed: r-4 .. r+TY+1
constexpr int VR  = TY + 2;    // v rows needed: r-2 .. r+TY-1
constexpr int HX  = TXF + 6;   // h1 cols needed: f-6 .. f+TXF-1
constexpr int NTHREADS = 256;

__device__ __forceinline__ float med3f(float a, float b, float c) {
    return fmaxf(fminf(a, b), fminf(fmaxf(a, b), c));
}

// median of 5: sort first 4 with the optimal 5-CE network, then med3(b,c,e) with b<=c
__device__ __forceinline__ float med5f(float a, float b, float c, float d, float e) {
    float t;
    t = fminf(a, b); b = fmaxf(a, b); a = t;
    t = fminf(c, d); d = fmaxf(c, d); c = t;
    t = fminf(a, c); c = fmaxf(a, c); a = t;
    t = fminf(b, d); d = fmaxf(b, d); b = t;
    t = fminf(b, c); c = fmaxf(b, c); b = t;
    // a<=b<=c<=d ; median5 = middle of {b,c,e}
    return fminf(c, fmaxf(b, e));
}

__global__ __launch_bounds__(NTHREADS) void fused_median_kernel(
        const float* __restrict__ img, float* __restrict__ out) {
    // A: x tile (XR x SX) then reused for v2 (TY x SX)
    // B: v tile (VR x SX) then reused for h1 (TY x HX)
    __shared__ float A[XR * SX];
    __shared__ float B[VR * SX];

    const int tid = threadIdx.x;
    const int r0 = blockIdx.y * TY;   // output row base
    const int f0 = blockIdx.x * TXF;  // output flat-col base

    // ---- Stage A: load clamped x halo -> A ----
    // Slot (lr, lf) holds x[clamp(r0-4+lr)][clamp_channelwise(f0-12+lf)].
    // Storing clamped values makes every later median window's edge-replication
    // automatic: reading slot k gives exactly x[clamp(k)].
    for (int idx = tid; idx < XR * SX; idx += NTHREADS) {
        int lr  = idx / SX;
        int lf  = idx - lr * SX;
        int rr  = r0 - 4 + lr;
        int rrc = min(max(rr, 0), NN - 1);
        int ffp = f0 + lf;            // = (f0-12+lf) + 12, always >= 0; 12 % 3 == 0
        int c3  = ffp / 3;
        int ch  = ffp - c3 * 3;
        int cc  = min(max(c3 - 4, 0), WW - 1);
        A[idx] = img[(size_t)(rrc + CROPC) * WFLAT + (cc * 3 + ch)];
    }
    __syncthreads();

    // ---- Stage B: vertical median5 -> B (v rows r0-2 .. r0+TY-1) ----
    for (int idx = tid; idx < VR * SX; idx += NTHREADS) {
        int lr = idx / SX;
        int lf = idx - lr * SX;
        const float* p = &A[lr * SX + lf];   // A row lr == global row (r0-2+lr)-2
        B[idx] = med5f(p[0], p[SX], p[2*SX], p[3*SX], p[4*SX]);
    }
    __syncthreads();

    // ---- Stage C: shift1 + vertical median3 -> A (v2 rows r0 .. r0+TY-1) ----
    // v2[0] = med(0,0,v0) = 0 ; v2[1] = med(0,v0,v1) ;
    // v2[N-1] = med(v[N-3],v[N-2],v[N-2]) = v[N-2] ; else med(v[r-2],v[r-1],v[r])
    for (int idx = tid; idx < TY * SX; idx += NTHREADS) {
        int lr = idx / SX;
        int lf = idx - lr * SX;
        int r  = r0 + lr;
        const float* p = &B[lr * SX + lf];   // B row lr == v[r-2]
        float o;
        if (r == 0)           o = 0.0f;
        else if (r == 1)      o = med3f(0.0f, p[SX], p[2*SX]);
        else if (r == NN - 1) o = p[SX];
        else                  o = med3f(p[0], p[SX], p[2*SX]);
        A[idx] = o;
    }
    __syncthreads();

    // ---- Stage D: horizontal median5 -> B (h1 flat cols f0-6 .. f0+TXF-1) ----
    // Column clamping is automatic: out-of-image v2 slots hold replicated columns.
    for (int idx = tid; idx < TY * HX; idx += NTHREADS) {
        int lr  = idx / HX;
        int lf2 = idx - lr * HX;
        const float* p = &A[lr * SX + lf2];  // slot col lf2 == flat (f0-6+lf2)-6
        B[lr * HX + lf2] = med5f(p[0], p[3], p[6], p[9], p[12]);
    }
    __syncthreads();

    // ---- Stage E: shift1 + horizontal median3 -> out ----
    // h2[c=0]=0 ; h2[c=1]=med(0,h1[0],h1[1]) ; h2[W-1]=h1[W-2] ; else med(h1[c-2..c])
    for (int idx = tid; idx < TY * TXF; idx += NTHREADS) {
        int lr = idx / TXF;
        int lf = idx - lr * TXF;
        int r  = r0 + lr;
        if (r >= NN) continue;
        int f = f0 + lf;
        int c = f / 3;
        const float* p = &B[lr * HX + lf];   // p[0]=h1[f-6], p[3]=h1[f-3], p[6]=h1[f]
        float o;
        if (c == 0)           o = 0.0f;
        else if (c == 1)      o = med3f(0.0f, p[3], p[6]);
        else if (c == WW - 1) o = p[3];
        else                  o = med3f(p[0], p[3], p[6]);
        out[(size_t)r * WFLAT + f] = o;
    }
}

extern "C" void kernel_launch(void* const* d_in, const int* in_sizes, int n_in,
                              void* d_out, int out_size, void* d_ws, size_t ws_size,
                              hipStream_t stream) {
    const float* img = (const float*)d_in[0];   // (2160, 3840, 3) fp32
    // d_in[1] = mask (unused by reference), d_in[2] = vertical_size (== 5)
    float* out = (float*)d_out;                 // (2154, 3840, 3) fp32
    dim3 grid(WFLAT / TXF, (NN + TY - 1) / TY); // 90 x 68 tiles
    fused_median_kernel<<<grid, NTHREADS, 0, stream>>>(img, out);
}

// Round 2
// 55.930 us; speedup vs baseline: 2.1579x; 2.1579x over previous
//
#include <hip/hip_runtime.h>

// Problem geometry (fixed by the reference)
#define HH    2160
#define WW    3840
#define CROPC 3
#define NN    (HH - 2*CROPC)   // 2154 output rows
#define WFLAT (WW * 3)         // 11520 flat columns

constexpr int TY    = 32;          // output rows per block
constexpr int TXF   = 192;         // output flat cols per block; 11520/192 = 60 exact
constexpr int SX    = TXF + 18;    // 210: halo 12 left (c-4) + 6 right (c+2)
constexpr int LSTR  = SX + 1;      // 211: odd LDS row stride -> bank spread
constexpr int NTH   = 256;
constexpr int TPR   = 8;           // phase-2 threads per row
constexpr int CHUNK = TXF / TPR;   // 24 flat cols/thread (mult of 3; 96 B -> 16B-aligned stores)

__device__ __forceinline__ float med3f(float a, float b, float c) {
    return fmaxf(fminf(a, b), fminf(fmaxf(a, b), c));
}
// median of 5: 4-element sort network + med3 merge (12 min/max)
__device__ __forceinline__ float med5f(float a, float b, float c, float d, float e) {
    float t;
    t = fminf(a, b); b = fmaxf(a, b); a = t;
    t = fminf(c, d); d = fmaxf(c, d); c = t;
    t = fminf(a, c); c = fmaxf(a, c); a = t;
    t = fminf(b, d); d = fmaxf(b, d); b = t;
    t = fminf(b, c); c = fmaxf(b, c); b = t;
    return fminf(c, fmaxf(b, e));
}

__global__ __launch_bounds__(NTH) void fused_median(const float* __restrict__ img,
                                                    float* __restrict__ out) {
    __shared__ float v2s[TY * LSTR];   // 27,008 B -> 5 blocks/CU

    const int tid = threadIdx.x;
    const int r0 = blockIdx.y * TY;
    const int f0 = blockIdx.x * TXF;

    // ---- Phase 1: vertical med5 + shift/med3, fully in registers (1 col/thread) ----
    // Column clamp baked in once; row clamp is uniform SALU per iteration.
    if (tid < SX) {
        const int ffp = f0 + tid;              // flat halo col + 12 (>= 0)
        const int c3  = ffp / 3;
        const int ch  = ffp - 3 * c3;
        const int cc  = min(max(c3 - 4, 0), WW - 1);
        const float* colp = img + (size_t)CROPC * WFLAT + (cc * 3 + ch);

        float x0=0.f, x1=0.f, x2=0.f, x3=0.f, x4=0.f, vm2=0.f, vm1=0.f;
        #pragma unroll
        for (int i = 0; i < TY + 6; ++i) {
            const int rr = min(max(r0 - 4 + i, 0), NN - 1);   // uniform
            const float xn = colp[(size_t)rr * WFLAT];
            x0 = x1; x1 = x2; x2 = x3; x3 = x4; x4 = xn;
            if (i >= 4) {                       // compile-time after unroll
                const float vc = med5f(x0, x1, x2, x3, x4);   // v[rz] with rz = r0+i-6
                if (i >= 6) {
                    const int rz = r0 + i - 6;
                    // v2[rz] = med3(v[rz-2], v[rz-1], v[rz]) with shift1 edge algebra:
                    //  rz==0 -> 0 ; rz==1 -> med3(0,v0,v1) ; rz==NN-1 -> v[NN-2]
                    float a = vm2, b = vm1;
                    if (rz == NN - 1) a = b;        // med3(b,b,vc) == b
                    if (rz == 1)      a = 0.f;
                    if (rz == 0)    { a = 0.f; b = 0.f; }     // med3(0,0,vc) == 0
                    v2s[(i - 6) * LSTR + tid] = med3f(a, b, vc);
                }
                vm2 = vm1; vm1 = vc;
            }
        }
    }
    __syncthreads();

    // ---- Phase 2: horizontal med5 + shift/med3, per-channel rolling in registers ----
    const int lr    = tid >> 3;          // LDS row 0..31
    const int kk    = tid & (TPR - 1);   // chunk 0..7
    const int r_out = r0 + lr;
    if (r_out >= NN) return;             // tail row-block guard (no barriers after this)

    const float* s = &v2s[lr * LSTR + kk * CHUNK];  // strip base = flat (fs - 12)
    const int cs = f0 / 3 + (CHUNK / 3) * kk;       // image col of first output
    const bool edge = (cs <= 1) || (cs + CHUNK / 3 - 1 >= WW - 1);

    float o[CHUNK];
    #pragma unroll
    for (int c = 0; c < 3; ++c) {
        float ss[14];
        #pragma unroll
        for (int j = 0; j < 14; ++j) ss[j] = s[3 * j + c];
        // h1 at image col (cs - 2 + m)
        float h[10];
        #pragma unroll
        for (int m = 0; m < 10; ++m)
            h[m] = med5f(ss[m], ss[m+1], ss[m+2], ss[m+3], ss[m+4]);
        // h2[cs+n] = med3(h1[n], h1[n+1], h1[n+2])
        if (!edge) {
            #pragma unroll
            for (int n = 0; n < 8; ++n)
                o[3 * n + c] = med3f(h[n], h[n+1], h[n+2]);
        } else {
            #pragma unroll
            for (int n = 0; n < 8; ++n) {
                const int ci = cs + n;
                float A = h[n], B = h[n+1];
                if (ci == WW - 1) A = B;            // result h1[ci-1]
                if (ci == 1)      A = 0.f;          // med3(0, h1[ci-1], h1[ci])
                if (ci == 0)    { A = 0.f; B = 0.f; } // -> 0
                o[3 * n + c] = med3f(A, B, h[n+2]);
            }
        }
    }

    // coalesced-ish 16B stores (fs*4 = 768*bx + 96*kk -> 16B aligned)
    float4* op = (float4*)(out + (size_t)r_out * WFLAT + f0 + kk * CHUNK);
    #pragma unroll
    for (int q = 0; q < CHUNK / 4; ++q)
        op[q] = make_float4(o[4*q], o[4*q+1], o[4*q+2], o[4*q+3]);
}

extern "C" void kernel_launch(void* const* d_in, const int* in_sizes, int n_in,
                              void* d_out, int out_size, void* d_ws, size_t ws_size,
                              hipStream_t stream) {
    const float* img = (const float*)d_in[0];   // (2160, 3840, 3) fp32
    // d_in[1] = mask (unused by reference), d_in[2] = vertical_size (== 5)
    float* out = (float*)d_out;                 // (2154, 3840, 3) fp32
    dim3 grid(WFLAT / TXF, (NN + TY - 1) / TY); // 60 x 68
    fused_median<<<grid, NTH, 0, stream>>>(img, out);
}

// Round 3
// 51.832 us; speedup vs baseline: 2.3285x; 1.0791x over previous
//
#include <hip/hip_runtime.h>

// Problem geometry (fixed by the reference)
#define HH    2160
#define WW    3840
#define CROPC 3
#define NN    (HH - 2*CROPC)   // 2154 output rows
#define WFLAT (WW * 3)         // 11520 flat columns

constexpr int TY    = 32;           // output rows per block
constexpr int TXF   = 192;          // output flat cols per block; 11520/192 = 60
constexpr int SX    = TXF + 18;     // 210 flat halo cols (12 left, 6 right)
constexpr int NTH   = 256;
constexpr int TPR   = 8;            // phase-2 threads per row
constexpr int XROWS = TY + 6;       // 38 input rows per tile

// De-interleaved LDS: 3 channel planes of [TY rows][PSTR cols], skewed bases.
constexpr int PC    = SX / 3 + 0;   // 70 per-channel cols held (cols c0h .. c0h+69)
constexpr int PSTR  = 76;           // row stride (mult of 4 for b128; 76%32=12 spreads banks)
constexpr int PLANE = TY * PSTR + 8; // 2440: +8 skew rotates bank phase per plane

__device__ __forceinline__ float med3f(float a, float b, float c) {
    return fmaxf(fminf(a, b), fminf(fmaxf(a, b), c));
}
// median of 5: 4-element sort network + med3 merge (12 min/max)
__device__ __forceinline__ float med5f(float a, float b, float c, float d, float e) {
    float t;
    t = fminf(a, b); b = fmaxf(a, b); a = t;
    t = fminf(c, d); d = fmaxf(c, d); c = t;
    t = fminf(a, c); c = fmaxf(a, c); a = t;
    t = fminf(b, d); d = fmaxf(b, d); b = t;
    t = fminf(b, c); c = fmaxf(b, c); b = t;
    return fminf(c, fmaxf(b, e));
}

__global__ __launch_bounds__(NTH) void fused_median(const float* __restrict__ img,
                                                    float* __restrict__ out) {
    __shared__ float v2s[3 * PLANE];   // 29,280 B -> 5 blocks/CU

    const int tid = threadIdx.x;
    const int r0 = blockIdx.y * TY;
    const int f0 = blockIdx.x * TXF;

    // ---- Phase 1: vertical med5 + shift/med3, registers only (1 flat col/thread) ----
    if (tid < SX) {
        const int ch   = tid % 3;              // f0,12 both mult of 3 -> channel = tid%3
        const int pcol = tid / 3;              // plane col 0..69 <-> img col c0h+pcol
        const int cc   = min(max(f0 / 3 - 4 + pcol, 0), WW - 1);  // clamped img col
        const float* colp = img + (size_t)CROPC * WFLAT + (cc * 3 + ch);

        // Batch ALL row loads first: 38 independent global loads in flight (MLP),
        // then compute. Static indices after unroll -> stays in VGPRs.
        float xv[XROWS];
        #pragma unroll
        for (int i = 0; i < XROWS; ++i) {
            const int rr = min(max(r0 - 4 + i, 0), NN - 1);   // wave-uniform
            xv[i] = colp[(size_t)rr * WFLAT];
        }

        float vm2 = 0.f, vm1 = 0.f;
        #pragma unroll
        for (int i = 4; i < XROWS; ++i) {
            const float vc = med5f(xv[i-4], xv[i-3], xv[i-2], xv[i-1], xv[i]); // v[r0+i-6]
            if (i >= 6) {
                const int rz = r0 + i - 6;
                // v2[rz] = med3(v[rz-2], v[rz-1], v[rz]); shift1 edge algebra:
                //  rz==0 -> 0 ; rz==1 -> med3(0,v0,v1) ; rz==NN-1 -> v[NN-2]
                float a = vm2, b = vm1;
                if (rz == NN - 1) a = b;
                if (rz == 1)      a = 0.f;
                if (rz == 0)    { a = 0.f; b = 0.f; }
                v2s[ch * PLANE + (i - 6) * PSTR + pcol] = med3f(a, b, vc);
            }
            vm2 = vm1; vm1 = vc;
        }
    }
    __syncthreads();

    // ---- Phase 2: horizontal med5 + shift/med3, per-channel stride-1 b128 reads ----
    const int lr    = tid >> 3;          // row 0..31
    const int kk    = tid & (TPR - 1);   // 8-col chunk 0..7
    const int r_out = r0 + lr;
    if (r_out >= NN) return;             // no barriers after this

    const int cbase = f0 / 3 + 8 * kk;   // first output img col (8 cols/thread)
    const bool edge = (cbase <= 1) || (cbase + 7 >= WW - 1);

    float o[24];
    #pragma unroll
    for (int c = 0; c < 3; ++c) {
        // plane cols 8kk .. 8kk+13 == img cols cbase-4 .. cbase+9 (clamped)
        const float* pb = &v2s[c * PLANE + lr * PSTR + 8 * kk];  // 16B aligned
        const float4 q0 = *(const float4*)(pb);
        const float4 q1 = *(const float4*)(pb + 4);
        const float4 q2 = *(const float4*)(pb + 8);
        const float4 q3 = *(const float4*)(pb + 12);
        const float ss[16] = {q0.x,q0.y,q0.z,q0.w, q1.x,q1.y,q1.z,q1.w,
                              q2.x,q2.y,q2.z,q2.w, q3.x,q3.y,q3.z,q3.w};
        float h[10];
        #pragma unroll
        for (int m = 0; m < 10; ++m)
            h[m] = med5f(ss[m], ss[m+1], ss[m+2], ss[m+3], ss[m+4]); // h1[cbase-2+m]
        if (!edge) {
            #pragma unroll
            for (int n = 0; n < 8; ++n)
                o[3*n + c] = med3f(h[n], h[n+1], h[n+2]);
        } else {
            #pragma unroll
            for (int n = 0; n < 8; ++n) {
                const int ci = cbase + n;
                float A = h[n], B = h[n+1];
                if (ci == WW - 1) A = B;
                if (ci == 1)      A = 0.f;
                if (ci == 0)    { A = 0.f; B = 0.f; }
                o[3*n + c] = med3f(A, B, h[n+2]);
            }
        }
    }

    // 6 aligned float4 stores (f0 + 24kk mult of 4)
    float4* op = (float4*)(out + (size_t)r_out * WFLAT + f0 + 24 * kk);
    #pragma unroll
    for (int q = 0; q < 6; ++q)
        op[q] = make_float4(o[4*q], o[4*q+1], o[4*q+2], o[4*q+3]);
}

extern "C" void kernel_launch(void* const* d_in, const int* in_sizes, int n_in,
                              void* d_out, int out_size, void* d_ws, size_t ws_size,
                              hipStream_t stream) {
    const float* img = (const float*)d_in[0];   // (2160, 3840, 3) fp32
    // d_in[1] = mask (unused by reference), d_in[2] = vertical_size (== 5)
    float* out = (float*)d_out;                 // (2154, 3840, 3) fp32
    dim3 grid(WFLAT / TXF, (NN + TY - 1) / TY); // 60 x 68
    fused_median<<<grid, NTH, 0, stream>>>(img, out);
}

// Round 4
// 49.148 us; speedup vs baseline: 2.4556x; 1.0546x over previous
//
#include <hip/hip_runtime.h>

// Problem geometry (fixed by the reference)
#define HH    2160
#define WW    3840
#define CROPC 3
#define NN    (HH - 2*CROPC)   // 2154 output rows
#define WFLAT (WW * 3)         // 11520 flat columns

constexpr int TY    = 16;           // output rows per block (small -> high occupancy)
constexpr int TXF   = 192;          // output flat cols per block; 11520/192 = 60
constexpr int SX    = TXF + 18;     // 210 flat halo cols (12 left, 6 right)
constexpr int NTH   = 256;
constexpr int TPR   = 16;           // phase-2 threads per row
constexpr int XROWS = TY + 6;       // 22 input rows per tile

// De-interleaved LDS: 3 channel planes of [TY rows][PSTR cols] (+8 skew per plane).
constexpr int PSTR  = 76;           // mult of 4 (b128-aligned rows); 76%32=12 spreads banks
constexpr int PLANE = TY * PSTR + 8; // 1224 dwords; total 3*1224*4 = 14,688 B -> 8 blocks/CU

__device__ __forceinline__ float med3f(float a, float b, float c) {
    return fmaxf(fminf(a, b), fminf(fmaxf(a, b), c));
}
// median of 5: 4-element sort network + med3 merge (12 min/max)
__device__ __forceinline__ float med5f(float a, float b, float c, float d, float e) {
    float t;
    t = fminf(a, b); b = fmaxf(a, b); a = t;
    t = fminf(c, d); d = fmaxf(c, d); c = t;
    t = fminf(a, c); c = fmaxf(a, c); a = t;
    t = fminf(b, d); d = fmaxf(b, d); b = t;
    t = fminf(b, c); c = fmaxf(b, c); b = t;
    return fminf(c, fmaxf(b, e));
}

__global__ __launch_bounds__(NTH, 8) void fused_median(const float* __restrict__ img,
                                                       float* __restrict__ out) {
    __shared__ float v2s[3 * PLANE];   // 14,688 B

    const int tid = threadIdx.x;
    const int r0 = blockIdx.y * TY;
    const int f0 = blockIdx.x * TXF;

    // ---- Phase 1: vertical med5 + shift/med3, registers only (1 flat col/thread) ----
    if (tid < SX) {
        const int ch   = tid % 3;              // f0 mult of 3 -> channel = tid%3
        const int pcol = tid / 3;              // plane col 0..69 <-> img col f0/3-4+pcol
        const int cc   = min(max(f0 / 3 - 4 + pcol, 0), WW - 1);  // clamped img col
        const float* colp = img + (size_t)CROPC * WFLAT + (cc * 3 + ch);

        // Batch ALL 22 row loads; sched_barrier pins them before the med network
        // so each wave keeps the full batch in flight (one latency exposure).
        float xv[XROWS];
        #pragma unroll
        for (int i = 0; i < XROWS; ++i) {
            const int rr = min(max(r0 - 4 + i, 0), NN - 1);   // wave-uniform
            xv[i] = colp[(size_t)rr * WFLAT];
        }
        __builtin_amdgcn_sched_barrier(0);

        float vm2 = 0.f, vm1 = 0.f;
        #pragma unroll
        for (int i = 4; i < XROWS; ++i) {
            const float vc = med5f(xv[i-4], xv[i-3], xv[i-2], xv[i-1], xv[i]); // v[r0+i-6]
            if (i >= 6) {
                const int rz = r0 + i - 6;
                // v2[rz] = med3(v[rz-2], v[rz-1], v[rz]); shift1 edge algebra:
                //  rz==0 -> 0 ; rz==1 -> med3(0,v0,v1) ; rz==NN-1 -> v[NN-2]
                float a = vm2, b = vm1;
                if (rz == NN - 1) a = b;
                if (rz == 1)      a = 0.f;
                if (rz == 0)    { a = 0.f; b = 0.f; }
                v2s[ch * PLANE + (i - 6) * PSTR + pcol] = med3f(a, b, vc);
            }
            vm2 = vm1; vm1 = vc;
        }
    }
    __syncthreads();

    // ---- Phase 2: horizontal med5 + shift/med3; 16 rows x 16 chunks of 4 img cols ----
    const int lr    = tid >> 4;          // row 0..15
    const int kk    = tid & (TPR - 1);   // chunk 0..15
    const int r_out = r0 + lr;
    if (r_out >= NN) return;             // no barriers after this

    const int cbase = f0 / 3 + 4 * kk;   // first output img col (4 cols/thread)
    const bool edge = (cbase <= 1) || (cbase + 3 >= WW - 1);

    float o[12];
    #pragma unroll
    for (int c = 0; c < 3; ++c) {
        // plane cols 4kk .. 4kk+9 == img cols cbase-4 .. cbase+5 (clamped)
        const float* pb = &v2s[c * PLANE + lr * PSTR + 4 * kk];  // 16B aligned
        const float4 q0 = *(const float4*)(pb);
        const float4 q1 = *(const float4*)(pb + 4);
        const float4 q2 = *(const float4*)(pb + 8);   // cols +8..+11 (use 8,9)
        const float ss[12] = {q0.x,q0.y,q0.z,q0.w, q1.x,q1.y,q1.z,q1.w,
                              q2.x,q2.y,q2.z,q2.w};
        float h[6];
        #pragma unroll
        for (int m = 0; m < 6; ++m)
            h[m] = med5f(ss[m], ss[m+1], ss[m+2], ss[m+3], ss[m+4]); // h1[cbase-2+m]
        if (!edge) {
            #pragma unroll
            for (int n = 0; n < 4; ++n)
                o[3*n + c] = med3f(h[n], h[n+1], h[n+2]);
        } else {
            #pragma unroll
            for (int n = 0; n < 4; ++n) {
                const int ci = cbase + n;
                float A = h[n], B = h[n+1];
                if (ci == WW - 1) A = B;
                if (ci == 1)      A = 0.f;
                if (ci == 0)    { A = 0.f; B = 0.f; }
                o[3*n + c] = med3f(A, B, h[n+2]);
            }
        }
    }

    // 3 aligned float4 stores (f0 + 12kk mult of 4)
    float4* op = (float4*)(out + (size_t)r_out * WFLAT + f0 + 12 * kk);
    #pragma unroll
    for (int q = 0; q < 3; ++q)
        op[q] = make_float4(o[4*q], o[4*q+1], o[4*q+2], o[4*q+3]);
}

extern "C" void kernel_launch(void* const* d_in, const int* in_sizes, int n_in,
                              void* d_out, int out_size, void* d_ws, size_t ws_size,
                              hipStream_t stream) {
    const float* img = (const float*)d_in[0];   // (2160, 3840, 3) fp32
    // d_in[1] = mask (unused by reference), d_in[2] = vertical_size (== 5)
    float* out = (float*)d_out;                 // (2154, 3840, 3) fp32
    dim3 grid(WFLAT / TXF, (NN + TY - 1) / TY); // 60 x 135
    fused_median<<<grid, NTH, 0, stream>>>(img, out);
}